// Round 2
// baseline (575.562 us; speedup 1.0000x reference)
//
#include <hip/hip_runtime.h>

#define DIMC 1024
#define NSEQ 8192
#define DH 64

typedef __attribute__((ext_vector_type(8))) short short8;
typedef __attribute__((ext_vector_type(4))) float f32x4;

__device__ __forceinline__ short f2bf(float f) {
  union { float f; unsigned u; } v; v.f = f;
  unsigned r = v.u + 0x7FFFu + ((v.u >> 16) & 1u);
  return (short)(r >> 16);
}

// pack two fp32 -> two bf16 (round-half-up): 2 adds + 1 perm
__device__ __forceinline__ unsigned pack_bf2(float a, float b) {
  union { float f; unsigned u; } va, vb;
  va.f = a; vb.f = b;
  unsigned ua = va.u + 0x8000u;
  unsigned ub = vb.u + 0x8000u;
  return (ua >> 16) | (ub & 0xFFFF0000u);
}

__device__ __forceinline__ void gload_lds16(const void* g, void* l) {
  __builtin_amdgcn_global_load_lds(
      (const __attribute__((address_space(1))) void*)g,
      (__attribute__((address_space(3))) void*)l, 16, 0, 0);
}

// ---------------- Stage 1: Gram matrices G[b,h] = X^T X (partials) ----------
// grid (32 chunks, 64 bh), block 64. Prefetch next tile's global loads before
// compute so the ~900cyc HBM latency hides behind 2048 FMA cycles.
__global__ __launch_bounds__(64) void gram_kernel(const float* __restrict__ x,
                                                  float* __restrict__ Gpart) {
  int chunk = blockIdx.x, bh = blockIdx.y;
  int b = bh >> 4, h = bh & 15;
  int t = threadIdx.x;
  __shared__ __align__(16) float rows[16 * 64];
  const float* xb = x + ((size_t)b * NSEQ) * DIMC + h * DH;
  int d0 = (t >> 3) * 8, e0 = (t & 7) * 8;
  float acc[8][8] = {};
  float4 v[4];
#pragma unroll
  for (int i = 0; i < 4; i++) {
    int f4 = i * 64 + t;
    v[i] = *(const float4*)(xb + (size_t)(chunk * 256 + (f4 >> 4)) * DIMC + (f4 & 15) * 4);
  }
  for (int it = 0; it < 16; it++) {
    __syncthreads();
#pragma unroll
    for (int i = 0; i < 4; i++) ((float4*)rows)[i * 64 + t] = v[i];
    __syncthreads();
    if (it < 15) {
      int nbase = chunk * 256 + (it + 1) * 16;
#pragma unroll
      for (int i = 0; i < 4; i++) {
        int f4 = i * 64 + t;
        v[i] = *(const float4*)(xb + (size_t)(nbase + (f4 >> 4)) * DIMC + (f4 & 15) * 4);
      }
    }
#pragma unroll
    for (int r = 0; r < 16; r++) {
      float xd[8], xe[8];
      *(float4*)&xd[0] = *(const float4*)&rows[r * 64 + d0];
      *(float4*)&xd[4] = *(const float4*)&rows[r * 64 + d0 + 4];
      *(float4*)&xe[0] = *(const float4*)&rows[r * 64 + e0];
      *(float4*)&xe[4] = *(const float4*)&rows[r * 64 + e0 + 4];
#pragma unroll
      for (int i = 0; i < 8; i++)
#pragma unroll
        for (int j = 0; j < 8; j++) acc[i][j] = fmaf(xd[i], xe[j], acc[i][j]);
    }
  }
  float* gp = Gpart + (size_t)chunk * (64 * 4096) + (size_t)bh * 4096;
#pragma unroll
  for (int i = 0; i < 8; i++)
#pragma unroll
    for (int j = 0; j < 8; j++) gp[(d0 + i) * 64 + e0 + j] = acc[i][j];
}

// ---------------- Stage 1b: reduce 32 partials -> G ----------
__global__ void reduce_g(const float* __restrict__ Gpart, float* __restrict__ G) {
  int i = blockIdx.x * 256 + threadIdx.x;  // 0..262143
  float s = 0.f;
#pragma unroll
  for (int p = 0; p < 32; p++) s += Gpart[(size_t)p * (64 * 4096) + i];
  G[i] = s;
}

// ---------------- Stage 2: WbigT[b][c][k] = (Wq^T Wk G Wv^T /N  Wo_h^T)^T ----
__global__ __launch_bounds__(256) void combine_kernel(
    const float* __restrict__ G, const float* __restrict__ Wq,
    const float* __restrict__ Wk, const float* __restrict__ Wv,
    const float* __restrict__ Wo, short* __restrict__ WbigT) {
  int bh = blockIdx.x, qt = blockIdx.y;
  int b = bh >> 4, h = bh & 15;
  int t = threadIdx.x;
  __shared__ __align__(16) float sG[4096];
  __shared__ __align__(16) float sW[4096];
  __shared__ __align__(16) float sA[4096];
  __shared__ __align__(16) float sM[4096];

  for (int i = t; i < 4096; i += 256) sG[i] = G[(size_t)bh * 4096 + i];
  for (int i = t; i < 4096; i += 256) sW[i] = Wk[i];
  __syncthreads();

  int d0 = (t >> 4) * 4, e0 = (t & 15) * 4;
  // T1 = Wk * G  -> sA
  {
    float a[4][4] = {};
    for (int fg = 0; fg < 16; fg++) {
      float wk[4][4], g4[4][4];
#pragma unroll
      for (int i = 0; i < 4; i++) *(float4*)wk[i] = *(const float4*)&sW[(d0 + i) * 64 + fg * 4];
#pragma unroll
      for (int ff = 0; ff < 4; ff++) *(float4*)g4[ff] = *(const float4*)&sG[(fg * 4 + ff) * 64 + e0];
#pragma unroll
      for (int i = 0; i < 4; i++)
#pragma unroll
        for (int ff = 0; ff < 4; ff++)
#pragma unroll
          for (int j = 0; j < 4; j++) a[i][j] = fmaf(wk[i][ff], g4[ff][j], a[i][j]);
    }
#pragma unroll
    for (int i = 0; i < 4; i++)
#pragma unroll
      for (int j = 0; j < 4; j++) sA[(d0 + i) * 64 + e0 + j] = a[i][j];
  }
  __syncthreads();
  for (int i = t; i < 4096; i += 256) sW[i] = Wv[i];
  __syncthreads();
  // T2 = T1 * Wv^T -> sG
  {
    float a[4][4] = {};
    for (int fgi = 0; fgi < 16; fgi++) {
      int fg = (fgi + (t & 15)) & 15;
      float t1[4][4], wv[4][4];
#pragma unroll
      for (int i = 0; i < 4; i++) *(float4*)t1[i] = *(const float4*)&sA[(d0 + i) * 64 + fg * 4];
#pragma unroll
      for (int j = 0; j < 4; j++) *(float4*)wv[j] = *(const float4*)&sW[(e0 + j) * 64 + fg * 4];
#pragma unroll
      for (int i = 0; i < 4; i++)
#pragma unroll
        for (int j = 0; j < 4; j++)
#pragma unroll
          for (int ff = 0; ff < 4; ff++) a[i][j] = fmaf(t1[i][ff], wv[j][ff], a[i][j]);
    }
    __syncthreads();
#pragma unroll
    for (int i = 0; i < 4; i++)
#pragma unroll
      for (int j = 0; j < 4; j++) sG[(d0 + i) * 64 + e0 + j] = a[i][j];
  }
  __syncthreads();
  for (int i = t; i < 4096; i += 256) sW[i] = Wq[i];
  __syncthreads();
  // M = Wq^T * T2 / N -> sM
  {
    float a[4][4] = {};
    for (int f = 0; f < 64; f++) {
      float wq[4], t2[4];
      *(float4*)wq = *(const float4*)&sW[f * 64 + d0];
      *(float4*)t2 = *(const float4*)&sG[f * 64 + e0];
#pragma unroll
      for (int i = 0; i < 4; i++)
#pragma unroll
        for (int j = 0; j < 4; j++) a[i][j] = fmaf(wq[i], t2[j], a[i][j]);
    }
#pragma unroll
    for (int i = 0; i < 4; i++)
#pragma unroll
      for (int j = 0; j < 4; j++) sM[(d0 + i) * 64 + e0 + j] = a[i][j] * (1.0f / 8192.0f);
  }
  __syncthreads();
  int dd0 = (t & 15) * 4, cl0 = (t >> 4) * 4;
  for (int cc = qt * 4; cc < qt * 4 + 4; cc++) {
    int c0 = cc * 64;
    for (int i = t; i < 4096; i += 256)
      sW[i] = Wo[(size_t)(c0 + (i >> 6)) * DIMC + h * DH + (i & 63)];
    __syncthreads();
    float a[4][4] = {};
    for (int egi = 0; egi < 16; egi++) {
      int eg = (egi + (t & 15)) & 15;
      float m4[4][4], wo4[4][4];
#pragma unroll
      for (int i = 0; i < 4; i++) *(float4*)m4[i] = *(const float4*)&sM[(dd0 + i) * 64 + eg * 4];
#pragma unroll
      for (int j = 0; j < 4; j++) *(float4*)wo4[j] = *(const float4*)&sW[(cl0 + j) * 64 + eg * 4];
#pragma unroll
      for (int i = 0; i < 4; i++)
#pragma unroll
        for (int j = 0; j < 4; j++)
#pragma unroll
          for (int ff = 0; ff < 4; ff++) a[i][j] = fmaf(m4[i][ff], wo4[j][ff], a[i][j]);
    }
#pragma unroll
    for (int j = 0; j < 4; j++)
#pragma unroll
      for (int i = 0; i < 4; i++)
        WbigT[((size_t)b << 20) + (size_t)(c0 + cl0 + j) * DIMC + h * DH + dd0 + i] =
            f2bf(a[i][j]);
    __syncthreads();
  }
}

// ---------------- Stage 3: out = x @ Wbig[b] + bo -------------------------
// 128x128 tile, BK=32. A: direct global->reg fp32 + packed bf16 cvt (no LDS).
// B: double-buffered LDS via global_load_lds x16, XOR-swizzled (conflict-free),
// dma for kt+1 issued AFTER the barrier -> in flight across compute, drained
// at the NEXT barrier. One barrier per iter.
__global__ __launch_bounds__(256, 3) void gemm_kernel(
    const float* __restrict__ x, const short* __restrict__ WbigT,
    const float* __restrict__ bo, float* __restrict__ out) {
  int bid = blockIdx.x;
  // XCD-aware swizzle: 4 m-panels x 8 n-panels per XCD (~4MB L2 footprint)
  int xcd = bid & 7, r = bid >> 3;
  int g = r >> 5, q = r & 31;
  int m_blk = g * 32 + xcd * 4 + (q >> 3);
  int n_blk = q & 7;
  int b = m_blk >> 6;
  int row0 = m_blk * 128;
  int c0 = n_blk * 128;

  __shared__ __align__(16) short Bs[2][128 * 32];

  int t = threadIdx.x;
  int lane = t & 63, wave = t >> 6;
  int wm = wave >> 1, wn = wave & 1;
  int quad = lane >> 4, ln = lane & 15;

  f32x4 acc[4][4];
#pragma unroll
  for (int i = 0; i < 4; i++)
#pragma unroll
    for (int j = 0; j < 4; j++) acc[i][j] = (f32x4){0.f, 0.f, 0.f, 0.f};

  const short* Bbase = WbigT + ((size_t)b << 20);
  const float* Abase = x + (size_t)(row0 + wm * 64 + ln) * DIMC + quad * 8;

  // dma dest lane-contiguous 16B; source chunk XOR-permuted within each 64B row
  int e_base[2], crow_[2], lc_[2];
#pragma unroll
  for (int L = 0; L < 2; L++) {
    int e = (wave * 2 + L) * 512 + lane * 8;
    e_base[L] = e;
    int crow = e >> 5;
    int p = (e >> 3) & 3;
    crow_[L] = crow;
    lc_[L] = p ^ ((crow >> 1) & 3);
  }

#define STAGE_B(KT, BUF)                                                        \
  {                                                                             \
    int k0s = (KT) * 32;                                                        \
    _Pragma("unroll") for (int L = 0; L < 2; L++) {                             \
      gload_lds16(Bbase + (size_t)(c0 + crow_[L]) * DIMC + k0s + lc_[L] * 8,    \
                  &Bs[BUF][e_base[L]]);                                         \
    }                                                                           \
  }

#define LOAD_A_RAW(KT, DST)                                                     \
  {                                                                             \
    int k0s = (KT) * 32;                                                        \
    _Pragma("unroll") for (int i = 0; i < 4; i++) {                             \
      const float* gp = Abase + (size_t)i * 16 * DIMC + k0s;                    \
      DST[i][0] = *(const float4*)gp;                                           \
      DST[i][1] = *(const float4*)(gp + 4);                                     \
    }                                                                           \
  }

#define CVT_A(SRC, AF)                                                          \
  {                                                                             \
    _Pragma("unroll") for (int i = 0; i < 4; i++) {                             \
      unsigned w0 = pack_bf2(SRC[i][0].x, SRC[i][0].y);                         \
      unsigned w1 = pack_bf2(SRC[i][0].z, SRC[i][0].w);                         \
      unsigned w2 = pack_bf2(SRC[i][1].x, SRC[i][1].y);                         \
      unsigned w3 = pack_bf2(SRC[i][1].z, SRC[i][1].w);                         \
      unsigned tmp[4] = {w0, w1, w2, w3};                                       \
      AF[i] = *(short8*)tmp;                                                    \
    }                                                                           \
  }

  float4 araw[4][2];
  short8 afrag[4];
  STAGE_B(0, 0);
  LOAD_A_RAW(0, araw);
  CVT_A(araw, afrag);

  for (int kt = 0; kt < 32; kt++) {
    __syncthreads();  // (a) all waves done reading Bs[(kt-1)&1]; (b) dma kt drained
    if (kt < 31) {
      STAGE_B(kt + 1, (kt + 1) & 1);
      LOAD_A_RAW(kt + 1, araw);  // in flight across the MFMAs below
    }
    const short* bs = Bs[kt & 1];
    short8 bfrag[4];
#pragma unroll
    for (int i = 0; i < 4; i++) {
      int brow = wn * 64 + i * 16 + ln;
      int pc = quad ^ ((brow >> 1) & 3);
      bfrag[i] = *(const short8*)&bs[brow * 32 + pc * 8];
    }
#pragma unroll
    for (int i = 0; i < 4; i++)
#pragma unroll
      for (int j = 0; j < 4; j++)
        acc[i][j] = __builtin_amdgcn_mfma_f32_16x16x32_bf16(afrag[i], bfrag[j], acc[i][j], 0, 0, 0);
    if (kt < 31) CVT_A(araw, afrag);
  }

  // epilogue: C/D layout col=lane&15, row=quad*4+reg (m89-verified)
  float bov[4];
#pragma unroll
  for (int j = 0; j < 4; j++) bov[j] = bo[c0 + wn * 64 + j * 16 + ln];
#pragma unroll
  for (int i = 0; i < 4; i++)
#pragma unroll
    for (int j = 0; j < 4; j++) {
      int col = c0 + wn * 64 + j * 16 + ln;
#pragma unroll
      for (int rr = 0; rr < 4; rr++) {
        int row = row0 + wm * 64 + i * 16 + quad * 4 + rr;
        out[(size_t)row * DIMC + col] = acc[i][j][rr] + bov[j];
      }
    }
#undef STAGE_B
#undef LOAD_A_RAW
#undef CVT_A
}

extern "C" void kernel_launch(void* const* d_in, const int* in_sizes, int n_in,
                              void* d_out, int out_size, void* d_ws, size_t ws_size,
                              hipStream_t stream) {
  const float* x  = (const float*)d_in[0];
  const float* Wq = (const float*)d_in[1];
  const float* Wk = (const float*)d_in[2];
  const float* Wv = (const float*)d_in[3];
  const float* Wo = (const float*)d_in[4];
  const float* bo = (const float*)d_in[5];
  float* out = (float*)d_out;

  // workspace layout: Gpart 32 MiB | G 1 MiB | WbigT 8 MiB  (41 MiB, proven OK)
  float* Gpart = (float*)d_ws;
  float* G     = (float*)((char*)d_ws + ((size_t)32 << 20));
  short* WbigT = (short*)((char*)d_ws + ((size_t)33 << 20));
  (void)in_sizes; (void)n_in; (void)out_size; (void)ws_size;

  gram_kernel<<<dim3(32, 64), 64, 0, stream>>>(x, Gpart);
  reduce_g<<<1024, 256, 0, stream>>>(Gpart, G);
  combine_kernel<<<dim3(64, 4), 256, 0, stream>>>(G, Wq, Wk, Wv, Wo, WbigT);
  gemm_kernel<<<2048, 256, 0, stream>>>(x, WbigT, bo, out);
}

// Round 3
// 378.597 us; speedup vs baseline: 1.5202x; 1.5202x over previous
//
#include <hip/hip_runtime.h>

#define DIMC 1024
#define NSEQ 8192
#define DH 64

typedef __attribute__((ext_vector_type(8))) short short8;
typedef __attribute__((ext_vector_type(4))) float f32x4;

__device__ __forceinline__ short f2bf(float f) {
  union { float f; unsigned u; } v; v.f = f;
  unsigned r = v.u + 0x7FFFu + ((v.u >> 16) & 1u);
  return (short)(r >> 16);
}

// pack two fp32 -> two bf16 (lo = a, hi = b)
__device__ __forceinline__ unsigned pack_bf2(float a, float b) {
  union { float f; unsigned u; } va, vb;
  va.f = a; vb.f = b;
  unsigned ua = va.u + 0x8000u;
  unsigned ub = vb.u + 0x8000u;
  return (ua >> 16) | (ub & 0xFFFF0000u);
}

__device__ __forceinline__ void gload_lds16(const void* g, void* l) {
  __builtin_amdgcn_global_load_lds(
      (const __attribute__((address_space(1))) void*)g,
      (__attribute__((address_space(3))) void*)l, 16, 0, 0);
}

// ---------------- Stage 1: Gram partials; optionally emit bf16 copy of x ----
// grid (32 chunks, 64 bh), block 64 (1 wave), global-load prefetch.
__global__ __launch_bounds__(64) void gram_kernel(const float* __restrict__ x,
                                                  float* __restrict__ Gpart,
                                                  short* __restrict__ xbf) {
  int chunk = blockIdx.x, bh = blockIdx.y;
  int b = bh >> 4, h = bh & 15;
  int t = threadIdx.x;
  __shared__ __align__(16) float rows[16 * 64];
  const float* xb = x + ((size_t)b * NSEQ) * DIMC + h * DH;
  short* xo = xbf ? xbf + ((size_t)b * NSEQ) * DIMC + h * DH : (short*)0;
  int d0 = (t >> 3) * 8, e0 = (t & 7) * 8;
  float acc[8][8] = {};
  float4 v[4];
#pragma unroll
  for (int i = 0; i < 4; i++) {
    int f4 = i * 64 + t;
    v[i] = *(const float4*)(xb + (size_t)(chunk * 256 + (f4 >> 4)) * DIMC + (f4 & 15) * 4);
  }
  for (int it = 0; it < 16; it++) {
    __syncthreads();
#pragma unroll
    for (int i = 0; i < 4; i++) ((float4*)rows)[i * 64 + t] = v[i];
    __syncthreads();
    if (xo) {
#pragma unroll
      for (int i = 0; i < 4; i++) {
        int f4 = i * 64 + t;
        int row = chunk * 256 + it * 16 + (f4 >> 4), col = (f4 & 15) * 4;
        uint2 pw = {pack_bf2(v[i].x, v[i].y), pack_bf2(v[i].z, v[i].w)};
        *(uint2*)(xo + (size_t)row * DIMC + col) = pw;
      }
    }
    if (it < 15) {
      int nbase = chunk * 256 + (it + 1) * 16;
#pragma unroll
      for (int i = 0; i < 4; i++) {
        int f4 = i * 64 + t;
        v[i] = *(const float4*)(xb + (size_t)(nbase + (f4 >> 4)) * DIMC + (f4 & 15) * 4);
      }
    }
#pragma unroll
    for (int r = 0; r < 16; r++) {
      float xd[8], xe[8];
      *(float4*)&xd[0] = *(const float4*)&rows[r * 64 + d0];
      *(float4*)&xd[4] = *(const float4*)&rows[r * 64 + d0 + 4];
      *(float4*)&xe[0] = *(const float4*)&rows[r * 64 + e0];
      *(float4*)&xe[4] = *(const float4*)&rows[r * 64 + e0 + 4];
#pragma unroll
      for (int i = 0; i < 8; i++)
#pragma unroll
        for (int j = 0; j < 8; j++) acc[i][j] = fmaf(xd[i], xe[j], acc[i][j]);
    }
  }
  float* gp = Gpart + (size_t)chunk * (64 * 4096) + (size_t)bh * 4096;
#pragma unroll
  for (int i = 0; i < 8; i++)
#pragma unroll
    for (int j = 0; j < 8; j++) gp[(d0 + i) * 64 + e0 + j] = acc[i][j];
}

// ---------------- Stage 1b: reduce 32 partials -> G ----------
__global__ void reduce_g(const float* __restrict__ Gpart, float* __restrict__ G) {
  int i = blockIdx.x * 256 + threadIdx.x;
  float s = 0.f;
#pragma unroll
  for (int p = 0; p < 32; p++) s += Gpart[(size_t)p * (64 * 4096) + i];
  G[i] = s;
}

// ---------------- Stage 2: WbigT[b][c][k] ----------------------------------
// grid (64 bh, 8), 2 c-blocks per block (2 blocks/CU for latency hiding).
__global__ __launch_bounds__(256) void combine_kernel(
    const float* __restrict__ G, const float* __restrict__ Wq,
    const float* __restrict__ Wk, const float* __restrict__ Wv,
    const float* __restrict__ Wo, short* __restrict__ WbigT) {
  int bh = blockIdx.x, qt = blockIdx.y;
  int b = bh >> 4, h = bh & 15;
  int t = threadIdx.x;
  __shared__ __align__(16) float sG[4096];
  __shared__ __align__(16) float sW[4096];
  __shared__ __align__(16) float sA[4096];
  __shared__ __align__(16) float sM[4096];

  for (int i = t; i < 4096; i += 256) sG[i] = G[(size_t)bh * 4096 + i];
  for (int i = t; i < 4096; i += 256) sW[i] = Wk[i];
  __syncthreads();

  int d0 = (t >> 4) * 4, e0 = (t & 15) * 4;
  // T1 = Wk * G -> sA
  {
    float a[4][4] = {};
    for (int fg = 0; fg < 16; fg++) {
      float wk[4][4], g4[4][4];
#pragma unroll
      for (int i = 0; i < 4; i++) *(float4*)wk[i] = *(const float4*)&sW[(d0 + i) * 64 + fg * 4];
#pragma unroll
      for (int ff = 0; ff < 4; ff++) *(float4*)g4[ff] = *(const float4*)&sG[(fg * 4 + ff) * 64 + e0];
#pragma unroll
      for (int i = 0; i < 4; i++)
#pragma unroll
        for (int ff = 0; ff < 4; ff++)
#pragma unroll
          for (int j = 0; j < 4; j++) a[i][j] = fmaf(wk[i][ff], g4[ff][j], a[i][j]);
    }
#pragma unroll
    for (int i = 0; i < 4; i++)
#pragma unroll
      for (int j = 0; j < 4; j++) sA[(d0 + i) * 64 + e0 + j] = a[i][j];
  }
  __syncthreads();
  for (int i = t; i < 4096; i += 256) sW[i] = Wv[i];
  __syncthreads();
  // T2 = T1 * Wv^T -> sG
  {
    float a[4][4] = {};
    for (int fgi = 0; fgi < 16; fgi++) {
      int fg = (fgi + (t & 15)) & 15;
      float t1[4][4], wv[4][4];
#pragma unroll
      for (int i = 0; i < 4; i++) *(float4*)t1[i] = *(const float4*)&sA[(d0 + i) * 64 + fg * 4];
#pragma unroll
      for (int j = 0; j < 4; j++) *(float4*)wv[j] = *(const float4*)&sW[(e0 + j) * 64 + fg * 4];
#pragma unroll
      for (int i = 0; i < 4; i++)
#pragma unroll
        for (int j = 0; j < 4; j++)
#pragma unroll
          for (int ff = 0; ff < 4; ff++) a[i][j] = fmaf(t1[i][ff], wv[j][ff], a[i][j]);
    }
    __syncthreads();
#pragma unroll
    for (int i = 0; i < 4; i++)
#pragma unroll
      for (int j = 0; j < 4; j++) sG[(d0 + i) * 64 + e0 + j] = a[i][j];
  }
  __syncthreads();
  for (int i = t; i < 4096; i += 256) sW[i] = Wq[i];
  __syncthreads();
  // M = Wq^T * T2 / N -> sM
  {
    float a[4][4] = {};
    for (int f = 0; f < 64; f++) {
      float wq[4], t2[4];
      *(float4*)wq = *(const float4*)&sW[f * 64 + d0];
      *(float4*)t2 = *(const float4*)&sG[f * 64 + e0];
#pragma unroll
      for (int i = 0; i < 4; i++)
#pragma unroll
        for (int j = 0; j < 4; j++) a[i][j] = fmaf(wq[i], t2[j], a[i][j]);
    }
#pragma unroll
    for (int i = 0; i < 4; i++)
#pragma unroll
      for (int j = 0; j < 4; j++) sM[(d0 + i) * 64 + e0 + j] = a[i][j] * (1.0f / 8192.0f);
  }
  __syncthreads();
  int dd0 = (t & 15) * 4, cl0 = (t >> 4) * 4;
  for (int cc = qt * 2; cc < qt * 2 + 2; cc++) {
    int c0 = cc * 64;
    for (int i = t; i < 4096; i += 256)
      sW[i] = Wo[(size_t)(c0 + (i >> 6)) * DIMC + h * DH + (i & 63)];
    __syncthreads();
    float a[4][4] = {};
    for (int egi = 0; egi < 16; egi++) {
      int eg = (egi + (t & 15)) & 15;
      float m4[4][4], wo4[4][4];
#pragma unroll
      for (int i = 0; i < 4; i++) *(float4*)m4[i] = *(const float4*)&sM[(dd0 + i) * 64 + eg * 4];
#pragma unroll
      for (int j = 0; j < 4; j++) *(float4*)wo4[j] = *(const float4*)&sW[(cl0 + j) * 64 + eg * 4];
#pragma unroll
      for (int i = 0; i < 4; i++)
#pragma unroll
        for (int j = 0; j < 4; j++)
#pragma unroll
          for (int ff = 0; ff < 4; ff++) a[i][j] = fmaf(m4[i][ff], wo4[j][ff], a[i][j]);
    }
    // packed 8B stores: 4 consecutive d per thread
#pragma unroll
    for (int j = 0; j < 4; j++) {
      uint2 pw = {pack_bf2(a[0][j], a[1][j]), pack_bf2(a[2][j], a[3][j])};
      *(uint2*)&WbigT[((size_t)b << 20) + (size_t)(c0 + cl0 + j) * DIMC + h * DH + dd0] = pw;
    }
    __syncthreads();
  }
}

// ---------------- Stage 3a: gemm, fp32-A fallback (round-1 + XOR swizzle) ---
__global__ __launch_bounds__(256, 3) void gemm_small(
    const float* __restrict__ x, const short* __restrict__ WbigT,
    const float* __restrict__ bo, float* __restrict__ out) {
  int bid = blockIdx.x;
  int xcd = bid & 7, r = bid >> 3;
  int g = r >> 5, q = r & 31;
  int m_blk = g * 32 + xcd * 4 + (q >> 3);
  int n_blk = q & 7;
  int b = m_blk >> 6;
  int row0 = m_blk * 128;
  int c0 = n_blk * 128;

  __shared__ __align__(16) short As[128 * 32];
  __shared__ __align__(16) short Bs[128 * 32];

  int t = threadIdx.x;
  int lane = t & 63, wave = t >> 6;
  int wm = wave >> 1, wn = wave & 1;
  int quad = lane >> 4, ln = lane & 15;

  f32x4 acc[4][4];
#pragma unroll
  for (int i = 0; i < 4; i++)
#pragma unroll
    for (int j = 0; j < 4; j++) acc[i][j] = (f32x4){0.f, 0.f, 0.f, 0.f};

  const short* Bbase = WbigT + ((size_t)b << 20);

  int e_base[2], crow_[2], lc_[2];
#pragma unroll
  for (int L = 0; L < 2; L++) {
    int e = (wave * 2 + L) * 512 + lane * 8;
    e_base[L] = e;
    int crow = e >> 5;
    crow_[L] = crow;
    lc_[L] = ((e >> 3) & 3) ^ ((crow >> 1) & 3);
  }

  for (int kt = 0; kt < 32; kt++) {
    int k0 = kt * 32;
    __syncthreads();
    // B tile: DMA, source XOR-permuted so physical slot p holds logical p^s
#pragma unroll
    for (int L = 0; L < 2; L++)
      gload_lds16(Bbase + (size_t)(c0 + crow_[L]) * DIMC + k0 + lc_[L] * 8, &Bs[e_base[L]]);
    // A tile: fp32 load -> bf16 pack -> swizzled ds_write_b128
#pragma unroll
    for (int qq = 0; qq < 2; qq++) {
      int elem = qq * 2048 + wave * 512 + lane * 8;
      int m = elem >> 5, kk = elem & 31;
      const float* gp = x + (size_t)(row0 + m) * DIMC + k0 + kk;
      float4 v0 = *(const float4*)gp;
      float4 v1 = *(const float4*)(gp + 4);
      unsigned w0 = pack_bf2(v0.x, v0.y), w1 = pack_bf2(v0.z, v0.w);
      unsigned w2 = pack_bf2(v1.x, v1.y), w3 = pack_bf2(v1.z, v1.w);
      unsigned tmp[4] = {w0, w1, w2, w3};
      int pe = ((elem >> 3) & 3) ^ ((m >> 1) & 3);
      *(short8*)&As[m * 32 + pe * 8] = *(short8*)tmp;
    }
    __syncthreads();
    short8 afrag[4], bfrag[4];
#pragma unroll
    for (int i = 0; i < 4; i++) {
      int ar = wm * 64 + i * 16 + ln;
      afrag[i] = *(const short8*)&As[ar * 32 + (quad ^ ((ar >> 1) & 3)) * 8];
      int br = wn * 64 + i * 16 + ln;
      bfrag[i] = *(const short8*)&Bs[br * 32 + (quad ^ ((br >> 1) & 3)) * 8];
    }
#pragma unroll
    for (int i = 0; i < 4; i++)
#pragma unroll
      for (int j = 0; j < 4; j++)
        acc[i][j] = __builtin_amdgcn_mfma_f32_16x16x32_bf16(afrag[i], bfrag[j], acc[i][j], 0, 0, 0);
  }

  float bov[4];
#pragma unroll
  for (int j = 0; j < 4; j++) bov[j] = bo[c0 + wn * 64 + j * 16 + ln];
#pragma unroll
  for (int i = 0; i < 4; i++)
#pragma unroll
    for (int j = 0; j < 4; j++) {
      int col = c0 + wn * 64 + j * 16 + ln;
#pragma unroll
      for (int rr = 0; rr < 4; rr++) {
        int row = row0 + wm * 64 + i * 16 + quad * 4 + rr;
        out[(size_t)row * DIMC + col] = acc[i][j][rr] + bov[j];
      }
    }
}

// ---------------- Stage 3b: gemm, bf16-A via DMA (m97 structure exactly) ----
__global__ __launch_bounds__(256, 3) void gemm_big(
    const short* __restrict__ xbf, const short* __restrict__ WbigT,
    const float* __restrict__ bo, float* __restrict__ out) {
  int bid = blockIdx.x;
  int xcd = bid & 7, r = bid >> 3;
  int g = r >> 5, q = r & 31;
  int m_blk = g * 32 + xcd * 4 + (q >> 3);
  int n_blk = q & 7;
  int b = m_blk >> 6;
  int row0 = m_blk * 128;
  int c0 = n_blk * 128;

  __shared__ __align__(16) short As[128 * 32];
  __shared__ __align__(16) short Bs[128 * 32];

  int t = threadIdx.x;
  int lane = t & 63, wave = t >> 6;
  int wm = wave >> 1, wn = wave & 1;
  int quad = lane >> 4, ln = lane & 15;

  f32x4 acc[4][4];
#pragma unroll
  for (int i = 0; i < 4; i++)
#pragma unroll
    for (int j = 0; j < 4; j++) acc[i][j] = (f32x4){0.f, 0.f, 0.f, 0.f};

  const short* Bbase = WbigT + ((size_t)b << 20);

  int e_base[2];
  const short* Asrc[2];
  const short* Bsrc[2];
#pragma unroll
  for (int L = 0; L < 2; L++) {
    int e = (wave * 2 + L) * 512 + lane * 8;
    e_base[L] = e;
    int row = e >> 5;
    int lc = ((e >> 3) & 3) ^ ((row >> 1) & 3);
    Asrc[L] = xbf + (size_t)(row0 + row) * DIMC + lc * 8;
    Bsrc[L] = Bbase + (size_t)(c0 + row) * DIMC + lc * 8;
  }

  for (int kt = 0; kt < 32; kt++) {
    int k0 = kt * 32;
    __syncthreads();
#pragma unroll
    for (int L = 0; L < 2; L++) gload_lds16(Asrc[L] + k0, &As[e_base[L]]);
#pragma unroll
    for (int L = 0; L < 2; L++) gload_lds16(Bsrc[L] + k0, &Bs[e_base[L]]);
    __syncthreads();
    short8 afrag[4], bfrag[4];
#pragma unroll
    for (int i = 0; i < 4; i++) {
      int ar = wm * 64 + i * 16 + ln;
      afrag[i] = *(const short8*)&As[ar * 32 + (quad ^ ((ar >> 1) & 3)) * 8];
      int br = wn * 64 + i * 16 + ln;
      bfrag[i] = *(const short8*)&Bs[br * 32 + (quad ^ ((br >> 1) & 3)) * 8];
    }
#pragma unroll
    for (int i = 0; i < 4; i++)
#pragma unroll
      for (int j = 0; j < 4; j++)
        acc[i][j] = __builtin_amdgcn_mfma_f32_16x16x32_bf16(afrag[i], bfrag[j], acc[i][j], 0, 0, 0);
  }

  float bov[4];
#pragma unroll
  for (int j = 0; j < 4; j++) bov[j] = bo[c0 + wn * 64 + j * 16 + ln];
#pragma unroll
  for (int i = 0; i < 4; i++)
#pragma unroll
    for (int j = 0; j < 4; j++) {
      int col = c0 + wn * 64 + j * 16 + ln;
#pragma unroll
      for (int rr = 0; rr < 4; rr++) {
        int row = row0 + wm * 64 + i * 16 + quad * 4 + rr;
        out[(size_t)row * DIMC + col] = acc[i][j][rr] + bov[j];
      }
    }
}

extern "C" void kernel_launch(void* const* d_in, const int* in_sizes, int n_in,
                              void* d_out, int out_size, void* d_ws, size_t ws_size,
                              hipStream_t stream) {
  const float* x  = (const float*)d_in[0];
  const float* Wq = (const float*)d_in[1];
  const float* Wk = (const float*)d_in[2];
  const float* Wv = (const float*)d_in[3];
  const float* Wo = (const float*)d_in[4];
  const float* bo = (const float*)d_in[5];
  float* out = (float*)d_out;
  (void)in_sizes; (void)n_in; (void)out_size;

  if (ws_size >= ((size_t)105 << 20)) {
    // big path: xbf 64 MiB | Gpart 32 MiB | G 1 MiB | WbigT 8 MiB
    short* xbf   = (short*)d_ws;
    float* Gpart = (float*)((char*)d_ws + ((size_t)64 << 20));
    float* G     = (float*)((char*)d_ws + ((size_t)96 << 20));
    short* WbigT = (short*)((char*)d_ws + ((size_t)97 << 20));
    gram_kernel<<<dim3(32, 64), 64, 0, stream>>>(x, Gpart, xbf);
    reduce_g<<<1024, 256, 0, stream>>>(Gpart, G);
    combine_kernel<<<dim3(64, 8), 256, 0, stream>>>(G, Wq, Wk, Wv, Wo, WbigT);
    gemm_big<<<2048, 256, 0, stream>>>(xbf, WbigT, bo, out);
  } else {
    // fallback: Gpart 32 MiB | G 1 MiB | WbigT 8 MiB (41 MiB, proven)
    float* Gpart = (float*)d_ws;
    float* G     = (float*)((char*)d_ws + ((size_t)32 << 20));
    short* WbigT = (short*)((char*)d_ws + ((size_t)33 << 20));
    gram_kernel<<<dim3(32, 64), 64, 0, stream>>>(x, Gpart, (short*)0);
    reduce_g<<<1024, 256, 0, stream>>>(Gpart, G);
    combine_kernel<<<dim3(64, 8), 256, 0, stream>>>(G, Wq, Wk, Wv, Wo, WbigT);
    gemm_small<<<2048, 256, 0, stream>>>(x, WbigT, bo, out);
  }
}